// Round 6
// baseline (120.750 us; speedup 1.0000x reference)
//
#include <hip/hip_runtime.h>
#include <math.h>

typedef float f32x4 __attribute__((ext_vector_type(4)));

#define NF 69u                        // floats per output row (1 + 68)
#define WROWS 32u                     // rows per wave-tile
#define WTILE_FLOATS (WROWS * NF)     // 2208 floats = 8832 B per wave
#define WTILE_F4 (WTILE_FLOATS / 4u)  // 552 float4s
#define NCHUNK 9u                     // ceil(552 / 64): 8 full + 1 masked
#define BLOCK 256u
#define WAVES 4u

// ---------------------------------------------------------------------------
// Kernel 1: per-axis feature tables, padded to stride 8 for aligned f32x4
// loads. tab8[c*8 + ft] x-axis; tab8[8*W + c*8 + ft] y-axis.
// ft in [0,5): norm,sign,sin,cos,rtan.
// ---------------------------------------------------------------------------
__global__ void pe_table_kernel(const int* __restrict__ hptr,
                                const int* __restrict__ wptr,
                                float* __restrict__ tab8) {
    const int H = *hptr;
    const int W = *wptr;
    const int total = W + H;
    for (int i = (int)(blockIdx.x * blockDim.x + threadIdx.x); i < total;
         i += (int)(gridDim.x * blockDim.x)) {
        const bool is_y = (i >= W);
        const int c = is_y ? (i - W) : i;
        const int size = is_y ? H : W;
        double norm = 0.0, angle = 0.0;
        if (size > 1) {
            const double r = (double)c / (double)(size - 1);
            norm = 2.0 * r - 1.0;
            angle = M_PI * r;
        }
        const double d = (double)c - 0.5 * (double)size;
        const float sgn = (d > 0.0) ? 1.0f : ((d < 0.0) ? -1.0f : 0.0f);
        const int base = (is_y ? 8 * W : 0) + 8 * c;
        tab8[base + 0] = (float)norm;
        tab8[base + 1] = sgn;
        tab8[base + 2] = (float)sin(angle);
        tab8[base + 3] = (float)cos(angle);
        tab8[base + 4] = (float)rint(tan(angle));
    }
}

// ---------------------------------------------------------------------------
// Kernel 2: wave-private 32-row tiles, zero barriers, 16 waves/CU.
// Split half-wave header: lanes 0-31 write x + x-features for row=lane,
// lanes 32-63 write y-features + one-hot pokes for row=lane-32.
// Store: 9-deep unrolled float4 copy, PLAIN stores (no NT hint).
// One-hot region is persistent-zero: poke before store, restore after.
// ---------------------------------------------------------------------------
__global__ __launch_bounds__(BLOCK) void pe_main_kernel(
    const float* __restrict__ x,
    const int* __restrict__ hptr, const int* __restrict__ wptr,
    const float* __restrict__ tab8,
    float* __restrict__ out, unsigned int Q /* = B*H*W rows */) {
    __shared__ __align__(16) float lds[WAVES][WTILE_FLOATS];  // 35328 B

    const unsigned int W = (unsigned int)*wptr;
    const unsigned int H = (unsigned int)*hptr;
    const unsigned int yoff8 = 8u * W;
    const unsigned int lane = threadIdx.x & 63u;
    const unsigned int wid = threadIdx.x >> 6;
    const unsigned int r = lane & 31u;          // row within tile
    const bool hi = lane >= 32u;                // upper half-wave?
    float* buf = lds[wid];
    float* row = buf + r * NF;

    // One-time zero of this wave's private buffer (wave-local, no barrier).
    {
        f32x4 z = {0.f, 0.f, 0.f, 0.f};
        f32x4* bp = (f32x4*)buf;
        for (unsigned int j = lane; j < WTILE_F4; j += 64u) bp[j] = z;
    }

    const unsigned int ntiles = (Q + WROWS - 1u) / WROWS;
    const unsigned int gw = blockIdx.x * WAVES + wid;   // global wave id
    const unsigned int nw = gridDim.x * WAVES;

    for (unsigned int T = gw; T < ntiles; T += nw) {
        const unsigned int q = T * WROWS + r;
        unsigned int w = 0u, h = 0u;
        const bool valid = q < Q;
        if (valid) {
            const unsigned int t = q / W;   // q = (b*H + h)*W + w
            w = q - t * W;
            h = t - (t / H) * H;
            if (!hi) {
                // x value + 5 x-axis features (slots 1,3,5,7,9)
                const f32x4 xa = *(const f32x4*)(tab8 + 8u * w);
                const float xa4 = tab8[8u * w + 4u];
                row[0] = x[q];
                row[1] = xa[0]; row[3] = xa[1];
                row[5] = xa[2]; row[7] = xa[3];
                row[9] = xa4;
            } else {
                // 5 y-axis features (slots 2,4,6,8,10) + one-hot pokes
                const f32x4 ya = *(const f32x4*)(tab8 + yoff8 + 8u * h);
                const float ya4 = tab8[yoff8 + 8u * h + 4u];
                row[2] = ya[0]; row[4]  = ya[1];
                row[6] = ya[2]; row[8]  = ya[3];
                row[10] = ya4;
                if (w < 29u) row[11u + w] = 1.0f;
                if (h < 29u) row[40u + h] = 1.0f;
            }
        }

        const unsigned int rem = Q - T * WROWS;
        const size_t obase = (size_t)T * (size_t)WTILE_FLOATS;
        const f32x4* lp = (const f32x4*)buf;
        f32x4* op = (f32x4*)(out + obase);      // 2208*T floats: 16B-aligned

        if (rem >= WROWS) {
            // ---- full tile: 9-deep unrolled batched copy, plain stores ----
            f32x4 v[NCHUNK];
#pragma unroll
            for (unsigned int j = 0u; j < NCHUNK; ++j) {
                const unsigned int idx = lane + 64u * j;
                if (j < NCHUNK - 1u || idx < WTILE_F4) v[j] = lp[idx];
            }
#pragma unroll
            for (unsigned int j = 0u; j < NCHUNK; ++j) {
                const unsigned int idx = lane + 64u * j;
                if (j < NCHUNK - 1u || idx < WTILE_F4) op[idx] = v[j];
            }
        } else {
            // ---- partial tail tile (not hit for the bench shape) ----
            const unsigned int nfl = rem * NF;
            const unsigned int n4 = nfl >> 2;
            for (unsigned int j = lane; j < n4; j += 64u) op[j] = lp[j];
            for (unsigned int j = (n4 << 2) + lane; j < nfl; j += 64u)
                out[obase + j] = buf[j];
        }

        // ---- restore poked one-hot slots to zero (upper half-wave) ----
        if (valid && hi) {
            if (w < 29u) row[11u + w] = 0.0f;
            if (h < 29u) row[40u + h] = 0.0f;
        }
    }
}

extern "C" void kernel_launch(void* const* d_in, const int* in_sizes, int n_in,
                              void* d_out, int out_size, void* d_ws, size_t ws_size,
                              hipStream_t stream) {
    const float* x = (const float*)d_in[0];
    const int* hptr = (const int*)d_in[1];
    const int* wptr = (const int*)d_in[2];
    float* out = (float*)d_out;
    float* tab8 = (float*)d_ws;  // (W+H)*8*4 B = 32 KB for the bench shape

    pe_table_kernel<<<8, 256, 0, stream>>>(hptr, wptr, tab8);

    const unsigned int Q = (unsigned int)in_sizes[0];  // B*H*W rows
    const unsigned int ntiles = (Q + WROWS - 1u) / WROWS;
    unsigned int blocks = (ntiles + WAVES - 1u) / WAVES;
    if (blocks > 2048u) blocks = 2048u;
    if (blocks == 0u) blocks = 1u;
    pe_main_kernel<<<blocks, BLOCK, 0, stream>>>(x, hptr, wptr, tab8, out, Q);
}

// Round 8
// 119.704 us; speedup vs baseline: 1.0087x; 1.0087x over previous
//
#include <hip/hip_runtime.h>
#include <math.h>

typedef float f32x4 __attribute__((ext_vector_type(4)));

#define NF 69u                         // floats per output row (1 + 68)
#define TROWS 64u                      // rows per block-tile (lane = row)
#define TILE_FLOATS (TROWS * NF)       // 4416
#define TILE_F4 (TILE_FLOATS / 4u)     // 1104
#define BLOCK 256u

// ---------------------------------------------------------------------------
// Kernel 1: per-axis feature tables, padded to stride 8.
// tab8[c*8 + ft] x-axis; tab8[8*W + c*8 + ft] y-axis; ft: norm,sign,sin,cos,rtan
// ---------------------------------------------------------------------------
__global__ void pe_table_kernel(const int* __restrict__ hptr,
                                const int* __restrict__ wptr,
                                float* __restrict__ tab8) {
    const int H = *hptr;
    const int W = *wptr;
    const int total = W + H;
    for (int i = (int)(blockIdx.x * blockDim.x + threadIdx.x); i < total;
         i += (int)(gridDim.x * blockDim.x)) {
        const bool is_y = (i >= W);
        const int c = is_y ? (i - W) : i;
        const int size = is_y ? H : W;
        double norm = 0.0, angle = 0.0;
        if (size > 1) {
            const double r = (double)c / (double)(size - 1);
            norm = 2.0 * r - 1.0;
            angle = M_PI * r;
        }
        const double d = (double)c - 0.5 * (double)size;
        const float sgn = (d > 0.0) ? 1.0f : ((d < 0.0) ? -1.0f : 0.0f);
        const int base = (is_y ? 8 * W : 0) + 8 * c;
        tab8[base + 0] = (float)norm;
        tab8[base + 1] = sgn;
        tab8[base + 2] = (float)sin(angle);
        tab8[base + 3] = (float)cos(angle);
        tab8[base + 4] = (float)rint(tan(angle));
    }
}

// Per-tile compute: ~3 LDS writes per thread. lane = row; waves split the 11
// header slots; waves 2/3 also poke the one-hot 1.0 and restore the slot
// poked 2 tiles ago in this buffer (pw/ph registers, per buffer).
__device__ __forceinline__ void pe_compute(
    float* __restrict__ buf, unsigned int T, unsigned int Q,
    unsigned int W, unsigned int H, unsigned int yoff8,
    bool pot, unsigned int lw,
    const float* __restrict__ x, const float* __restrict__ tab8,
    unsigned int lane, unsigned int wv,
    unsigned int& pw, unsigned int& ph) {
    const unsigned int q = T * TROWS + lane;
    const bool valid = q < Q;
    unsigned int w, h;
    if (pot) {                       // W,H powers of two: no div emulation
        w = q & (W - 1u);
        h = (q >> lw) & (H - 1u);
    } else {
        const unsigned int t = q / W;
        w = q - t * W;
        h = t - (t / H) * H;
    }
    float* row = buf + lane * NF;
    const float* tx = tab8 + 8u * w;
    const float* ty = tab8 + yoff8 + 8u * h;
    if (wv == 0u) {
        if (valid) { row[0] = x[q]; row[1] = tx[0]; row[2] = ty[0]; }
    } else if (wv == 1u) {
        if (valid) { row[3] = tx[1]; row[4] = ty[1]; row[5] = tx[2]; }
    } else if (wv == 2u) {
        if (valid) { row[6] = ty[2]; row[7] = tx[3]; }
        if (pw < 29u) row[11u + pw] = 0.0f;            // restore old poke
        const unsigned int npw = (valid && w < 29u) ? w : 0xFFFFFFFFu;
        if (npw < 29u) row[11u + npw] = 1.0f;          // new poke
        pw = npw;
    } else {
        if (valid) { row[8] = ty[3]; row[9] = tx[4]; row[10] = ty[4]; }
        if (ph < 29u) row[40u + ph] = 0.0f;
        const unsigned int nph = (valid && h < 29u) ? h : 0xFFFFFFFFu;
        if (nph < 29u) row[40u + nph] = 1.0f;
        ph = nph;
    }
}

// ---------------------------------------------------------------------------
// Kernel 2: double-buffered pipeline, one lgkm-only barrier per tile,
// block-cooperative NT store phase, persistent-zero one-hot region.
// ---------------------------------------------------------------------------
__global__ __launch_bounds__(BLOCK) void pe_main_kernel(
    const float* __restrict__ x,
    const int* __restrict__ hptr, const int* __restrict__ wptr,
    const float* __restrict__ tab8,
    float* __restrict__ out, unsigned int Q /* = B*H*W rows */) {
    __shared__ __align__(16) float lds[2][TILE_FLOATS];  // 35328 B

    const unsigned int W = (unsigned int)*wptr;
    const unsigned int H = (unsigned int)*hptr;
    const unsigned int yoff8 = 8u * W;
    const bool pot = ((W & (W - 1u)) == 0u) && ((H & (H - 1u)) == 0u);
    // log2(W), only used when pot (W is a nonzero power of two there).
    const unsigned int lw = pot ? (unsigned int)(__ffs((int)W) - 1) : 0u;
    const unsigned int lane = threadIdx.x & 63u;
    const unsigned int wv = threadIdx.x >> 6;
    const unsigned int ntiles = (Q + TROWS - 1u) / TROWS;
    const unsigned int g = gridDim.x;

    // One-time zero of both buffers (covers the one-hot region).
    {
        f32x4 z = {0.f, 0.f, 0.f, 0.f};
        f32x4* bp = (f32x4*)&lds[0][0];
        for (unsigned int j = threadIdx.x; j < 2u * TILE_F4; j += BLOCK)
            bp[j] = z;
    }
    __syncthreads();

    unsigned int T = blockIdx.x;
    if (T >= ntiles) return;  // uniform per block

    unsigned int pw0 = 0xFFFFFFFFu, ph0 = 0xFFFFFFFFu;
    unsigned int pw1 = 0xFFFFFFFFu, ph1 = 0xFFFFFFFFu;
    pe_compute(lds[0], T, Q, W, H, yoff8, pot, lw, x, tab8, lane, wv, pw0, ph0);
    unsigned int cur = 0u;

    for (; T < ntiles; T += g) {
        // LDS-only barrier: global NT stores stay in flight across it.
        asm volatile("s_waitcnt lgkmcnt(0)\n\ts_barrier" ::: "memory");

        const unsigned int rem = Q - T * TROWS;
        const size_t obase = (size_t)T * (size_t)TILE_FLOATS;
        const f32x4* lp = (const f32x4*)(cur ? lds[1] : lds[0]);
        f32x4* op = (f32x4*)(out + obase);   // 4416*T floats: 16B-aligned

        if (rem >= TROWS) {
            // full tile: 4 + 1-masked unrolled batched copy
            const unsigned int t0 = threadIdx.x;
            const bool m = t0 < (TILE_F4 - 4u * BLOCK);  // 80
            f32x4 v0 = lp[t0];
            f32x4 v1 = lp[t0 + 256u];
            f32x4 v2 = lp[t0 + 512u];
            f32x4 v3 = lp[t0 + 768u];
            f32x4 v4;
            if (m) v4 = lp[t0 + 1024u];
            __builtin_nontemporal_store(v0, op + t0);
            __builtin_nontemporal_store(v1, op + t0 + 256u);
            __builtin_nontemporal_store(v2, op + t0 + 512u);
            __builtin_nontemporal_store(v3, op + t0 + 768u);
            if (m) __builtin_nontemporal_store(v4, op + t0 + 1024u);
        } else {
            // partial tail tile (not hit for the bench shape)
            const unsigned int nfl = rem * NF;
            const unsigned int n4 = nfl >> 2;
            const float* lf = (const float*)lp;
            for (unsigned int j = threadIdx.x; j < n4; j += BLOCK)
                __builtin_nontemporal_store(lp[j], op + j);
            for (unsigned int j = (n4 << 2) + threadIdx.x; j < nfl; j += BLOCK)
                __builtin_nontemporal_store(lf[j], out + obase + j);
        }

        // compute next tile into the other buffer (uniform branch selects
        // the per-buffer poke-tracking registers; no runtime-indexed array)
        const unsigned int Tn = T + g;
        if (Tn < ntiles) {
            if (cur == 0u)
                pe_compute(lds[1], Tn, Q, W, H, yoff8, pot, lw, x, tab8,
                           lane, wv, pw1, ph1);
            else
                pe_compute(lds[0], Tn, Q, W, H, yoff8, pot, lw, x, tab8,
                           lane, wv, pw0, ph0);
        }
        cur ^= 1u;
    }
}

extern "C" void kernel_launch(void* const* d_in, const int* in_sizes, int n_in,
                              void* d_out, int out_size, void* d_ws, size_t ws_size,
                              hipStream_t stream) {
    const float* x = (const float*)d_in[0];
    const int* hptr = (const int*)d_in[1];
    const int* wptr = (const int*)d_in[2];
    float* out = (float*)d_out;
    float* tab8 = (float*)d_ws;  // (W+H)*8*4 B = 32 KB for the bench shape

    pe_table_kernel<<<8, 256, 0, stream>>>(hptr, wptr, tab8);

    const unsigned int Q = (unsigned int)in_sizes[0];  // B*H*W rows
    const unsigned int ntiles = (Q + TROWS - 1u) / TROWS;
    unsigned int blocks = ntiles < 2048u ? ntiles : 2048u;
    if (blocks == 0u) blocks = 1u;
    pe_main_kernel<<<blocks, BLOCK, 0, stream>>>(x, hptr, wptr, tab8, out, Q);
}